// Round 1
// baseline (270.388 us; speedup 1.0000x reference)
//
#include <hip/hip_runtime.h>

#define Bn 256
#define Tn 256
#define Hn 16
#define Dn 88
#define LOG16 2.7725887222397811f

// ---------------------------------------------------------------------------
// Kernel 1: emission likelihoods.
// grid = (Bn*Tn)/64 = 1024 blocks x 256 threads. Block covers 64 consecutive
// t of a single b (b = blockIdx>>2). Produces:
//   Ebuf[b,t,h] = exp(emit[b,t,h] - max_h emit[b,t,:])
//   Msum[b]    += max_h emit[b,t,:]   for t < len_b   (atomic)
// ---------------------------------------------------------------------------
__global__ __launch_bounds__(256) void emit_kernel(
    const float* __restrict__ seq,
    const float* __restrict__ probs_y,
    const int*   __restrict__ lengths,
    float* __restrict__ Ebuf,
    float* __restrict__ Msum)
{
    __shared__ __align__(16) float lut[Dn * 64]; // [d][pc][h], 22528 B
    __shared__ int pcs[64 * 89];                 // [pair][d], stride 89 (bank pad)
    const int tid = threadIdx.x;

    // Phase A: build Bernoulli log-likelihood LUT from probs_y (H,2,D).
    for (int i = tid; i < Dn * 64; i += 256) {
        int h = i & 15, pcc = (i >> 4) & 3, d = i >> 6;
        int prev = pcc >> 1, cur = pcc & 1;
        float p = probs_y[(h * 2 + prev) * Dn + d];
        lut[i] = cur ? __logf(p) : __logf(1.0f - p);
    }

    // Phase B1: (prev,cur) codes for this block's 64 rows, pre-shifted to a
    // LUT byte offset: code = d*64 + prev*32 + cur*16.
    const int pidx0 = blockIdx.x * 64;
    for (int e = tid; e < 64 * Dn; e += 256) {
        int pair = e / Dn;
        int d = e - pair * Dn;
        int pidx = pidx0 + pair;
        int t = pidx & (Tn - 1);
        float cf = seq[(size_t)pidx * Dn + d];
        float pf = (t > 0) ? seq[(size_t)pidx * Dn - Dn + d] : 0.0f;
        pcs[pair * 89 + d] = (d << 6) + ((pf > 0.5f) ? 32 : 0) + ((cf > 0.5f) ? 16 : 0);
    }
    __syncthreads();

    // Phase B2: 4 threads per (b,t) row, each accumulating 4 h's via b128 LUT reads.
    const int pair = tid >> 2;
    const int h4i  = tid & 3;
    const int pidx = pidx0 + pair;
    const int t = pidx & (Tn - 1);
    const int b = pidx >> 8;
    float4 acc = {0.f, 0.f, 0.f, 0.f};
    #pragma unroll 8
    for (int d = 0; d < Dn; ++d) {
        int base = pcs[pair * 89 + d];
        const float4 v = *(const float4*)(lut + base + (h4i << 2));
        acc.x += v.x; acc.y += v.y; acc.z += v.z; acc.w += v.w;
    }
    float mx = fmaxf(fmaxf(acc.x, acc.y), fmaxf(acc.z, acc.w));
    mx = fmaxf(mx, __shfl_xor(mx, 1, 4));
    mx = fmaxf(mx, __shfl_xor(mx, 2, 4));
    float4 E;
    E.x = __expf(acc.x - mx); E.y = __expf(acc.y - mx);
    E.z = __expf(acc.z - mx); E.w = __expf(acc.w - mx);
    *(float4*)(Ebuf + (size_t)pidx * Hn + (h4i << 2)) = E;
    if (h4i == 0) {
        if (t < lengths[b]) atomicAdd(&Msum[b], mx);
    }
}

// ---------------------------------------------------------------------------
// Kernel 2: scaled linear-space forward recursion.
// grid = 64 blocks x 64 threads. ONE wave per block (required: we use
// lgkm-only waits instead of __syncthreads so vmcnt prefetch survives).
// Each 16-lane group owns one b; lane j owns column j of P; the full
// a-vector is replicated into every lane's registers via an LDS all-gather.
// ---------------------------------------------------------------------------
__global__ __launch_bounds__(64) void forward_kernel(
    const float* __restrict__ Ebuf,
    const float* __restrict__ Msum,
    const float* __restrict__ probs_x,
    const int*   __restrict__ lengths,
    float* __restrict__ out)
{
    __shared__ __align__(16) float sh[64];
    const int lane = threadIdx.x;
    const int g = lane >> 4, j = lane & 15;
    const int b = blockIdx.x * 4 + g;
    int len = lengths[b];
    len = min(max(len, 0), Tn);

    float pc[16];
    #pragma unroll
    for (int i = 0; i < 16; ++i) pc[i] = probs_x[i * Hn + j];

    float av[16];
    #pragma unroll
    for (int i = 0; i < 16; ++i) av[i] = 0.0f;
    av[0] = 1.0f;                       // alpha0 = onehot(state 0) in linear space

    float L = Msum[b];                  // all max-shifts pre-accumulated
    const float* Ep = Ebuf + (size_t)b * Tn * Hn + j;

    // depth-4 software prefetch of E (covers L2/L3 latency across iterations)
    float eb[4];
    #pragma unroll
    for (int k = 0; k < 4; ++k) eb[k] = (k < len) ? Ep[k * Hn] : 0.0f;

    #pragma unroll 4
    for (int t = 0; t < len; ++t) {
        float e = eb[t & 3];
        eb[t & 3] = (t + 4 < len) ? Ep[(t + 4) * Hn] : 0.0f;

        // s = (P^T a)_j  -- 16-tap dot, 4 independent accumulator chains
        float s0 = av[0] * pc[0], s1 = av[1] * pc[1];
        float s2 = av[2] * pc[2], s3 = av[3] * pc[3];
        #pragma unroll
        for (int i = 4; i < 16; i += 4) {
            s0 = fmaf(av[i + 0], pc[i + 0], s0);
            s1 = fmaf(av[i + 1], pc[i + 1], s1);
            s2 = fmaf(av[i + 2], pc[i + 2], s2);
            s3 = fmaf(av[i + 3], pc[i + 3], s3);
        }
        float an = ((s0 + s1) + (s2 + s3)) * e;

        // all-gather the 16 new a's into every lane of the group
        sh[lane] = an;
        __builtin_amdgcn_s_waitcnt(0xC07F); // lgkmcnt(0) only; vmcnt untouched
        const float4* shv = (const float4*)(sh + (g << 4));
        float4 v0 = shv[0], v1 = shv[1], v2 = shv[2], v3 = shv[3];
        av[0] = v0.x; av[1] = v0.y; av[2]  = v0.z; av[3]  = v0.w;
        av[4] = v1.x; av[5] = v1.y; av[6]  = v1.z; av[7]  = v1.w;
        av[8] = v2.x; av[9] = v2.y; av[10] = v2.z; av[11] = v2.w;
        av[12] = v3.x; av[13] = v3.y; av[14] = v3.z; av[15] = v3.w;
        __builtin_amdgcn_s_waitcnt(0xC07F); // reads drained before next write

        // renormalize every 8 steps (sum decays >= 0.038/step -> safe)
        if ((t & 7) == 7) {
            float S = 0.0f;
            #pragma unroll
            for (int i = 0; i < 16; ++i) S += av[i];
            float r = 1.0f / S;
            #pragma unroll
            for (int i = 0; i < 16; ++i) av[i] *= r;
            L += __logf(S);
        }
    }

    float S = 0.0f;
    #pragma unroll
    for (int i = 0; i < 16; ++i) S += av[i];
    // lse_h(alpha) = L + log(sum a); masked tail contributes (T-len)*log(H)
    float res = L + __logf(S) + (float)(Tn - len) * LOG16;
    if (j == 0) atomicAdd(out, res);
}

extern "C" void kernel_launch(void* const* d_in, const int* in_sizes, int n_in,
                              void* d_out, int out_size, void* d_ws, size_t ws_size,
                              hipStream_t stream) {
    const float* seq     = (const float*)d_in[0];
    const int*   lengths = (const int*)  d_in[1];
    const float* probs_x = (const float*)d_in[2];
    const float* probs_y = (const float*)d_in[3];
    float* out  = (float*)d_out;
    float* Ebuf = (float*)d_ws;                          // Bn*Tn*Hn floats = 4 MB
    float* Msum = Ebuf + (size_t)Bn * Tn * Hn;           // Bn floats

    hipMemsetAsync(d_out, 0, sizeof(float) * out_size, stream);
    hipMemsetAsync(Msum, 0, sizeof(float) * Bn, stream);
    emit_kernel<<<(Bn * Tn) / 64, 256, 0, stream>>>(seq, probs_y, lengths, Ebuf, Msum);
    forward_kernel<<<Bn / 4, 64, 0, stream>>>(Ebuf, Msum, probs_x, lengths, out);
}

// Round 2
// 256.804 us; speedup vs baseline: 1.0529x; 1.0529x over previous
//
#include <hip/hip_runtime.h>

#define Bn 256
#define Tn 256
#define Hn 16
#define Dn 88
#define LOG16 2.7725887222397811f

// ---------------------------------------------------------------------------
// DPP helpers: row_ror rotations within each 16-lane row. Self-calibrated use.
// ---------------------------------------------------------------------------
template<int CTRL>
__device__ __forceinline__ float dppf(float x) {
    return __int_as_float(__builtin_amdgcn_update_dpp(
        0, __float_as_int(x), CTRL, 0xF, 0xF, true));
}
#define GATHER16(dst, s)                                                     \
    dst[0] = (s);                                                            \
    dst[1] = dppf<0x128>(dst[0]);                                            \
    dst[2] = dppf<0x124>(dst[0]); dst[3]  = dppf<0x124>(dst[1]);             \
    dst[4] = dppf<0x122>(dst[0]); dst[5]  = dppf<0x122>(dst[1]);             \
    dst[6] = dppf<0x122>(dst[2]); dst[7]  = dppf<0x122>(dst[3]);             \
    dst[8] = dppf<0x121>(dst[0]); dst[9]  = dppf<0x121>(dst[1]);             \
    dst[10] = dppf<0x121>(dst[2]); dst[11] = dppf<0x121>(dst[3]);            \
    dst[12] = dppf<0x121>(dst[4]); dst[13] = dppf<0x121>(dst[5]);            \
    dst[14] = dppf<0x121>(dst[6]); dst[15] = dppf<0x121>(dst[7]);

__device__ __forceinline__ float rowsum16(float v) {
    v += dppf<0x128>(v); v += dppf<0x124>(v);
    v += dppf<0x122>(v); v += dppf<0x121>(v);
    return v;
}

// ---------------------------------------------------------------------------
// Kernel 0: Bernoulli log-likelihood LUT, computed ONCE.
// LUTg[d*64 + pc*16 + h], pc = prev*2 + cur.
// ---------------------------------------------------------------------------
__global__ __launch_bounds__(256) void lut_kernel(const float* __restrict__ probs_y,
                                                  float* __restrict__ LUTg) {
    for (int i = threadIdx.x; i < Dn * 64; i += 256) {
        int h = i & 15, pc = (i >> 4) & 3, d = i >> 6;
        int prev = pc >> 1, cur = pc & 1;
        float p = probs_y[(h * 2 + prev) * Dn + d];
        LUTg[i] = cur ? __logf(p) : __logf(1.0f - p);
    }
}

__device__ __forceinline__ void row_mask(const float* rp,
                                         unsigned& m0, unsigned& m1, unsigned& m2) {
    m0 = m1 = m2 = 0;
    #pragma unroll
    for (int jj = 0; jj < 22; ++jj) {
        float4 f = ((const float4*)rp)[jj];
        unsigned nib = (f.x > 0.5f ? 1u : 0u) | (f.y > 0.5f ? 2u : 0u) |
                       (f.z > 0.5f ? 4u : 0u) | (f.w > 0.5f ? 8u : 0u);
        const int base = jj * 4;
        if (base < 32)      m0 |= nib << base;
        else if (base < 64) m1 |= nib << (base - 32);
        else                m2 |= nib << (base - 64);
    }
}

// ---------------------------------------------------------------------------
// Kernel 1: emissions. 1024 blocks x 256 threads; block = 64 rows of one b.
// Row bits live in REGISTERS (3+3 u32); only the 22.5KB LUT is in LDS, so
// the inner loop's single ds_read_b128 has a register-computed address
// (no LDS->LDS dependency) and occupancy is LDS-limited at ~6 blocks/CU.
// ---------------------------------------------------------------------------
__global__ __launch_bounds__(256) void emit_kernel(
    const float* __restrict__ seq,
    const float* __restrict__ LUTg,
    const int*   __restrict__ lengths,
    float* __restrict__ Ebuf,
    float* __restrict__ Msum)
{
    __shared__ __align__(16) float lut[Dn * 64]; // 22528 B
    __shared__ uint4 smask[65];                  // cur-masks of rows -1..63
    const int tid = threadIdx.x;
    const int pidx0 = blockIdx.x * 64;

    if (tid < 64) {
        unsigned m0, m1, m2;
        row_mask(seq + (size_t)(pidx0 + tid) * Dn, m0, m1, m2);
        smask[tid + 1] = make_uint4(m0, m1, m2, 0);
    } else {
        for (int i = tid - 64; i < Dn * 64; i += 192) lut[i] = LUTg[i];
        if (tid == 64) {
            unsigned m0 = 0, m1 = 0, m2 = 0;
            if ((pidx0 & (Tn - 1)) > 0)
                row_mask(seq + (size_t)(pidx0 - 1) * Dn, m0, m1, m2);
            smask[0] = make_uint4(m0, m1, m2, 0);
        }
    }
    __syncthreads();

    const int p = tid >> 2, h4i = tid & 3;
    const int pidx = pidx0 + p;
    const int t = pidx & (Tn - 1);
    const int b = pidx >> 8;
    const uint4 cm = smask[p + 1];
    const uint4 pm = smask[p];            // row-1's cur mask (zeros if t==0)

    const float4* lv = (const float4*)lut;
    float4 acc = {0.f, 0.f, 0.f, 0.f};
    unsigned wc, wp;
    wc = cm.x; wp = pm.x;
    #pragma unroll 8
    for (int d = 0; d < 32; ++d) {
        int idx = (d << 4) + (((wp >> d) & 1u) << 3) + (((wc >> d) & 1u) << 2) + h4i;
        float4 v = lv[idx];
        acc.x += v.x; acc.y += v.y; acc.z += v.z; acc.w += v.w;
    }
    wc = cm.y; wp = pm.y;
    #pragma unroll 8
    for (int d = 0; d < 32; ++d) {
        int idx = ((d + 32) << 4) + (((wp >> d) & 1u) << 3) + (((wc >> d) & 1u) << 2) + h4i;
        float4 v = lv[idx];
        acc.x += v.x; acc.y += v.y; acc.z += v.z; acc.w += v.w;
    }
    wc = cm.z; wp = pm.z;
    #pragma unroll 8
    for (int d = 0; d < 24; ++d) {
        int idx = ((d + 64) << 4) + (((wp >> d) & 1u) << 3) + (((wc >> d) & 1u) << 2) + h4i;
        float4 v = lv[idx];
        acc.x += v.x; acc.y += v.y; acc.z += v.z; acc.w += v.w;
    }

    float mx = fmaxf(fmaxf(acc.x, acc.y), fmaxf(acc.z, acc.w));
    mx = fmaxf(mx, __shfl_xor(mx, 1, 4));
    mx = fmaxf(mx, __shfl_xor(mx, 2, 4));
    float4 E;
    E.x = __expf(acc.x - mx); E.y = __expf(acc.y - mx);
    E.z = __expf(acc.z - mx); E.w = __expf(acc.w - mx);
    ((float4*)Ebuf)[(pidx << 2) + h4i] = E;
    if (h4i == 0 && t < lengths[b]) atomicAdd(&Msum[b], mx);
}

// ---------------------------------------------------------------------------
// Kernel 2: forward recursion, DPP all-gather (zero LDS, zero barriers).
// 64 blocks x 64 threads; 16-lane row per b; lane j holds a_j.
// The rotation network's lane permutation is self-calibrated at init.
// ---------------------------------------------------------------------------
__global__ __launch_bounds__(64) void forward_kernel(
    const float* __restrict__ Ebuf,
    const float* __restrict__ Msum,
    const float* __restrict__ probs_x,
    const int*   __restrict__ lengths,
    float* __restrict__ out)
{
    const int lane = threadIdx.x & 63;
    const int j = lane & 15;
    const int b = blockIdx.x * 4 + (lane >> 4);
    int len = lengths[b];
    len = min(max(len, 0), Tn);

    // calibrate: run the gather network on float(j) to learn source lanes
    float cal[16];
    GATHER16(cal, (float)j);
    float pcr[16];
    #pragma unroll
    for (int k = 0; k < 16; ++k) pcr[k] = probs_x[((int)cal[k]) * Hn + j];

    float a = (j == 0) ? 1.0f : 0.0f;   // alpha0 one-hot, linear space
    float L = Msum[b];
    const float* Ep = Ebuf + ((size_t)b << 12) + j;

    float eb[8];
    #pragma unroll
    for (int k = 0; k < 8; ++k) eb[k] = Ep[k << 4];

    int lenmax = max(len, __shfl_xor(len, 16));
    lenmax = max(lenmax, __shfl_xor(lenmax, 32));

    #pragma unroll 8
    for (int t = 0; t < lenmax; ++t) {
        float e = eb[t & 7];
        int tn = t + 8; tn = (tn < Tn) ? tn : (Tn - 1);
        eb[t & 7] = Ep[tn << 4];

        float y[16];
        GATHER16(y, a);
        float s0 = y[0] * pcr[0], s1 = y[1] * pcr[1];
        float s2 = y[2] * pcr[2], s3 = y[3] * pcr[3];
        #pragma unroll
        for (int k = 4; k < 16; k += 4) {
            s0 = fmaf(y[k + 0], pcr[k + 0], s0);
            s1 = fmaf(y[k + 1], pcr[k + 1], s1);
            s2 = fmaf(y[k + 2], pcr[k + 2], s2);
            s3 = fmaf(y[k + 3], pcr[k + 3], s3);
        }
        float an = ((s0 + s1) + (s2 + s3)) * e;
        a = (t < len) ? an : a;          // freeze finished groups

        if ((t & 7) == 7) {              // renorm: identity on L + log(sum a)
            float S = rowsum16(a);
            a *= (1.0f / S);
            L += __logf(S);
        }
    }

    float S = rowsum16(a);
    float res = L + __logf(S) + (float)(Tn - len) * LOG16;
    if (j == 0) atomicAdd(out, res);
}

extern "C" void kernel_launch(void* const* d_in, const int* in_sizes, int n_in,
                              void* d_out, int out_size, void* d_ws, size_t ws_size,
                              hipStream_t stream) {
    const float* seq     = (const float*)d_in[0];
    const int*   lengths = (const int*)  d_in[1];
    const float* probs_x = (const float*)d_in[2];
    const float* probs_y = (const float*)d_in[3];
    float* out  = (float*)d_out;
    float* Ebuf = (float*)d_ws;                          // 1M floats = 4 MB
    float* Msum = Ebuf + (size_t)Bn * Tn * Hn;           // 256 floats
    float* LUTg = Msum + Bn;                             // 5632 floats

    hipMemsetAsync(d_out, 0, sizeof(float) * out_size, stream);
    hipMemsetAsync(Msum, 0, sizeof(float) * Bn, stream);
    lut_kernel<<<1, 256, 0, stream>>>(probs_y, LUTg);
    emit_kernel<<<(Bn * Tn) / 64, 256, 0, stream>>>(seq, LUTg, lengths, Ebuf, Msum);
    forward_kernel<<<Bn / 4, 64, 0, stream>>>(Ebuf, Msum, probs_x, lengths, out);
}

// Round 3
// 128.025 us; speedup vs baseline: 2.1120x; 2.0059x over previous
//
#include <hip/hip_runtime.h>

#define Bn 256
#define Tn 256
#define Hn 16
#define Dn 88
#define LOG16 2.7725887222397811f

// ---------------------------------------------------------------------------
// DPP helpers: row_ror rotations within 16-lane rows; self-calibrated usage.
// ---------------------------------------------------------------------------
template<int CTRL>
__device__ __forceinline__ float dppf(float x) {
    return __int_as_float(__builtin_amdgcn_update_dpp(
        0, __float_as_int(x), CTRL, 0xF, 0xF, true));
}
#define GATHER16(dst, s)                                                     \
    dst[0] = (s);                                                            \
    dst[1] = dppf<0x128>(dst[0]);                                            \
    dst[2] = dppf<0x124>(dst[0]); dst[3]  = dppf<0x124>(dst[1]);             \
    dst[4] = dppf<0x122>(dst[0]); dst[5]  = dppf<0x122>(dst[1]);             \
    dst[6] = dppf<0x122>(dst[2]); dst[7]  = dppf<0x122>(dst[3]);             \
    dst[8] = dppf<0x121>(dst[0]); dst[9]  = dppf<0x121>(dst[1]);             \
    dst[10] = dppf<0x121>(dst[2]); dst[11] = dppf<0x121>(dst[3]);            \
    dst[12] = dppf<0x121>(dst[4]); dst[13] = dppf<0x121>(dst[5]);            \
    dst[14] = dppf<0x121>(dst[6]); dst[15] = dppf<0x121>(dst[7]);

__device__ __forceinline__ float rowsum16(float v) {
    v += dppf<0x128>(v); v += dppf<0x124>(v);
    v += dppf<0x122>(v); v += dppf<0x121>(v);
    return v;
}

// pack the 4 nibbles of a word (bits 0-3 of each byte) into low 16 bits
__device__ __forceinline__ unsigned compress4(unsigned w) {
    unsigned y = (w | (w >> 4)) & 0x00FF00FFu;
    return (y | (y >> 8)) & 0xFFFFu;
}

// ---------------------------------------------------------------------------
// One block per sequence b. 256 threads.
//  A: build 22.5KB Bernoulli log-lik LUT in LDS (from probs_y).
//  0: coalesced load of seq[b] (88KB), nibble-pack into 6KB LDS bit array.
//  1: emissions -> Esh (LDS, scaled exp) + Msh (row maxes). No global traffic.
//  2: wave 0 runs the scaled linear-space forward recursion (DPP all-gather),
//     adds lse + masked-tail closed form, one atomicAdd per block.
// ---------------------------------------------------------------------------
__global__ __launch_bounds__(256) void fused_kernel(
    const float* __restrict__ seq,
    const int*   __restrict__ lengths,
    const float* __restrict__ probs_x,
    const float* __restrict__ probs_y,
    float* __restrict__ out)
{
    __shared__ __align__(16) float lut[Dn * 64];   // 22528 B  [d][pc][h]
    __shared__ unsigned nibW[Tn * 6];              //  6144 B  4 bits/elem
    __shared__ __align__(16) float Esh[Tn * Hn];   // 16384 B
    __shared__ float Msh[Tn];                      //  1024 B

    const int tid = threadIdx.x;
    const int b = blockIdx.x;
    const float4* seqv = (const float4*)(seq + (size_t)b * Tn * Dn);

    // ---- phase A: LUT ----
    for (int i = tid; i < Dn * 64; i += 256) {
        int h = i & 15, pc = (i >> 4) & 3, d = i >> 6;
        float p = probs_y[(h * 2 + (pc >> 1)) * Dn + d];
        lut[i] = (pc & 1) ? __logf(p) : __logf(1.0f - p);
    }

    // ---- phase 0: nibble pack (coalesced) ----
    ((unsigned short*)nibW)[tid * 12 + 11] = 0;        // zero pad bytes 22..23
    #pragma unroll
    for (int k = 0; k < 22; ++k) {
        int f = tid + (k << 8);                        // flat float4 index
        int t = f / 22, jj = f - t * 22;
        float4 v = seqv[f];
        unsigned nib = (v.x > 0.5f ? 1u : 0u) | (v.y > 0.5f ? 2u : 0u) |
                       (v.z > 0.5f ? 4u : 0u) | (v.w > 0.5f ? 8u : 0u);
        ((unsigned char*)nibW)[t * 24 + jj] = (unsigned char)nib;
    }
    __syncthreads();

    // ---- phase 1: emissions into LDS ----
    const float4* lv = (const float4*)lut;
    #pragma unroll
    for (int r = 0; r < 4; ++r) {
        int task = (r << 8) + tid;
        int t = task >> 2, h4i = task & 3;
        unsigned cw0, cw1, cw2, pw0, pw1, pw2;
        {
            unsigned c0 = compress4(nibW[t * 6 + 0]), c1 = compress4(nibW[t * 6 + 1]);
            unsigned c2 = compress4(nibW[t * 6 + 2]), c3 = compress4(nibW[t * 6 + 3]);
            unsigned c4 = compress4(nibW[t * 6 + 4]), c5 = compress4(nibW[t * 6 + 5]);
            cw0 = c0 | (c1 << 16); cw1 = c2 | (c3 << 16); cw2 = c4 | (c5 << 16);
        }
        if (t > 0) {
            unsigned c0 = compress4(nibW[t * 6 - 6]), c1 = compress4(nibW[t * 6 - 5]);
            unsigned c2 = compress4(nibW[t * 6 - 4]), c3 = compress4(nibW[t * 6 - 3]);
            unsigned c4 = compress4(nibW[t * 6 - 2]), c5 = compress4(nibW[t * 6 - 1]);
            pw0 = c0 | (c1 << 16); pw1 = c2 | (c3 << 16); pw2 = c4 | (c5 << 16);
        } else { pw0 = pw1 = pw2 = 0; }

        float4 acc = {0.f, 0.f, 0.f, 0.f};
        #pragma unroll 8
        for (int d = 0; d < 32; ++d) {
            int idx = (d << 4) + (((pw0 >> d) & 1u) << 3) + (((cw0 >> d) & 1u) << 2) + h4i;
            float4 v = lv[idx];
            acc.x += v.x; acc.y += v.y; acc.z += v.z; acc.w += v.w;
        }
        #pragma unroll 8
        for (int d = 0; d < 32; ++d) {
            int idx = ((d + 32) << 4) + (((pw1 >> d) & 1u) << 3) + (((cw1 >> d) & 1u) << 2) + h4i;
            float4 v = lv[idx];
            acc.x += v.x; acc.y += v.y; acc.z += v.z; acc.w += v.w;
        }
        #pragma unroll 8
        for (int d = 0; d < 24; ++d) {
            int idx = ((d + 64) << 4) + (((pw2 >> d) & 1u) << 3) + (((cw2 >> d) & 1u) << 2) + h4i;
            float4 v = lv[idx];
            acc.x += v.x; acc.y += v.y; acc.z += v.z; acc.w += v.w;
        }

        float mx = fmaxf(fmaxf(acc.x, acc.y), fmaxf(acc.z, acc.w));
        mx = fmaxf(mx, __shfl_xor(mx, 1, 4));
        mx = fmaxf(mx, __shfl_xor(mx, 2, 4));
        float4 E;
        E.x = __expf(acc.x - mx); E.y = __expf(acc.y - mx);
        E.z = __expf(acc.z - mx); E.w = __expf(acc.w - mx);
        ((float4*)Esh)[(t << 2) + h4i] = E;
        if (h4i == 0) Msh[t] = mx;
    }
    __syncthreads();

    // ---- phase 2: forward recursion, wave 0 only ----
    if (tid >= 64) return;
    const int j = tid & 15;
    int len = lengths[b];
    len = min(max(len, 0), Tn);

    float cal[16];
    GATHER16(cal, (float)j);                    // learn the network's permutation
    float pcr[16];
    #pragma unroll
    for (int k = 0; k < 16; ++k) pcr[k] = probs_x[((int)cal[k]) * Hn + j];

    float msum = 0.0f;
    #pragma unroll
    for (int k = 0; k < 16; ++k) {
        int t = j + (k << 4);
        float m = Msh[t];
        msum += (t < len) ? m : 0.0f;
    }
    float L = rowsum16(msum);

    float a = (j == 0) ? 1.0f : 0.0f;
    float eb[8];
    #pragma unroll
    for (int k = 0; k < 8; ++k) eb[k] = Esh[(k << 4) + j];

    #pragma unroll 8
    for (int t = 0; t < len; ++t) {
        float e = eb[t & 7];
        int tn = t + 8; tn = (tn < Tn) ? tn : (Tn - 1);
        eb[t & 7] = Esh[(tn << 4) + j];

        float y[16];
        GATHER16(y, a);
        float s0 = y[0] * pcr[0], s1 = y[1] * pcr[1];
        float s2 = y[2] * pcr[2], s3 = y[3] * pcr[3];
        #pragma unroll
        for (int k = 4; k < 16; k += 4) {
            s0 = fmaf(y[k + 0], pcr[k + 0], s0);
            s1 = fmaf(y[k + 1], pcr[k + 1], s1);
            s2 = fmaf(y[k + 2], pcr[k + 2], s2);
            s3 = fmaf(y[k + 3], pcr[k + 3], s3);
        }
        a = ((s0 + s1) + (s2 + s3)) * e;

        if ((t & 7) == 7) {                     // renorm (identity on L+log S)
            float S = rowsum16(a);
            a *= (1.0f / S);
            L += __logf(S);
        }
    }

    float S = rowsum16(a);
    float res = L + __logf(S) + (float)(Tn - len) * LOG16;
    if (tid == 0) atomicAdd(out, res);
}

extern "C" void kernel_launch(void* const* d_in, const int* in_sizes, int n_in,
                              void* d_out, int out_size, void* d_ws, size_t ws_size,
                              hipStream_t stream) {
    const float* seq     = (const float*)d_in[0];
    const int*   lengths = (const int*)  d_in[1];
    const float* probs_x = (const float*)d_in[2];
    const float* probs_y = (const float*)d_in[3];
    float* out = (float*)d_out;

    hipMemsetAsync(d_out, 0, sizeof(float) * out_size, stream);
    fused_kernel<<<Bn, 256, 0, stream>>>(seq, lengths, probs_x, probs_y, out);
}